// Round 16
// baseline (265.370 us; speedup 1.0000x reference)
//
#include <hip/hip_runtime.h>
#include <math.h>

// B=2048, A=32 -> R=65536 rows. E_IN=160, H=128, HE=256, NACT=32, G=3, TAU=1.
#define R_TOTAL 65536

typedef __attribute__((ext_vector_type(8))) short short8_t;
typedef __attribute__((ext_vector_type(4))) short short4_t;
typedef __attribute__((ext_vector_type(4))) float f32x4_t;

__device__ __forceinline__ float frcp_(float x) { return __builtin_amdgcn_rcpf(x); }
__device__ __forceinline__ float fast_sigmoid(float x) { return frcp_(1.f + __expf(-x)); }
__device__ __forceinline__ float fast_tanh(float x) {
  float xc = fminf(fmaxf(x, -15.f), 15.f);
  float t = __expf(2.f * xc);
  return (t - 1.f) * frcp_(t + 1.f);
}

__device__ __forceinline__ short f2bf(float x) {
  unsigned u = __float_as_uint(x);
  u += 0x7fff + ((u >> 16) & 1);   // round-to-nearest-even
  return (short)(u >> 16);
}
__device__ __forceinline__ float bf2f(short s) {
  return __uint_as_float(((unsigned)(unsigned short)s) << 16);
}

// async global->LDS 16B per lane (dest must be wave-uniform base + lane*16)
__device__ __forceinline__ void async_cp16(const short* gsrc, short* ldst) {
  __builtin_amdgcn_global_load_lds(
      (const __attribute__((address_space(1))) void*)gsrc,
      (__attribute__((address_space(3))) void*)ldst, 16, 0, 0);
}

// Load 8 consecutive floats -> bf16 fragment (RNE).
__device__ __forceinline__ void load_afrag(const float* p, short8_t& h) {
  float4 u0 = *(const float4*)p;
  float4 u1 = *(const float4*)(p + 4);
  float v[8] = {u0.x, u0.y, u0.z, u0.w, u1.x, u1.y, u1.z, u1.w};
#pragma unroll
  for (int i = 0; i < 8; ++i) h[i] = f2bf(v[i]);
}

#define MFMA(ACC, A, B) ACC = __builtin_amdgcn_mfma_f32_16x16x32_bf16(A, B, ACC, 0, 0, 0)

// ---------------- fused fragment pack: all weights in one launch ----------------
struct PackSeg {
  const float* W;
  int Ksrc, N, KK, blk0, nblk;
  size_t off;
};
struct PackArgs { PackSeg s[11]; };

__global__ __launch_bounds__(256) void pack_all_kernel(PackArgs a, short* __restrict__ P) {
  const int b = blockIdx.x;
  PackSeg seg = a.s[0];
#pragma unroll
  for (int i = 1; i < 11; ++i)
    if (b >= a.s[i].blk0) seg = a.s[i];
  int p = (b - seg.blk0) * 256 + threadIdx.x;
  int i = p & 7, lane = (p >> 3) & 63, kk = (p >> 9) % seg.KK, ct = p / (seg.KK * 512);
  int e = kk * 32 + (lane >> 4) * 8 + i;
  int c = ct * 16 + (lane & 15);
  float w = (e < seg.Ksrc) ? seg.W[(size_t)e * seg.N + c] : 0.f;
  P[seg.off + p] = f2bf(w);
}

// ---------------- fused fc1 + GRU: 64-row blocks, 1 m-frag/wave (grid 1024) ----------------
__global__ __launch_bounds__(256, 4) void gru_fused_kernel(
    const float* __restrict__ inputs, const float* __restrict__ Hin,
    const short* __restrict__ Fc1p, const float* __restrict__ fc1b,
    const short* __restrict__ WiP, const short* __restrict__ WhP,
    const float* __restrict__ gbi, const float* __restrict__ gbh,
    float* __restrict__ Hout) {
  __shared__ short mid[64 * 128];   // 16 KB, 256B rows, XOR-swizzled
  const int tid = threadIdx.x;
  const int wave = tid >> 6, lane = tid & 63;
  const int cl = lane & 15, kg = lane >> 4;
  const int row0g = blockIdx.x * 64 + wave * 16;
  const int row0l = wave * 16;

  // ---- stage 1: x = relu(inputs @ fc1 + b) ----
  {
    short8_t ah1[5];
    {
      const float* ap = inputs + (size_t)(row0g + cl) * 160;
#pragma unroll
      for (int kk = 0; kk < 5; ++kk) load_afrag(ap + kk * 32 + kg * 8, ah1[kk]);
    }
    for (int ct = 0; ct < 8; ++ct) {
      f32x4_t a0 = (f32x4_t){0.f, 0.f, 0.f, 0.f};
#pragma unroll
      for (int kk = 0; kk < 5; ++kk) {
        short8_t b_h = *(const short8_t*)(Fc1p + (((size_t)ct * 5 + kk) * 64 + lane) * 8);
        MFMA(a0, ah1[kk], b_h);
      }
      int col = ct * 16 + cl;
      float bv = fc1b[col];
      int c2hi = (col * 2) & ~15, c2lo = (col * 2) & 15;
#pragma unroll
      for (int j = 0; j < 4; ++j) {
        float v0 = fmaxf(a0[j] + bv, 0.f);
        int r0 = row0l + kg * 4 + j;
        int ad0 = ((r0 * 256 + c2hi) ^ ((r0 & 7) << 4)) + c2lo;
        *(short*)((char*)mid + ad0) = f2bf(v0);
      }
    }
  }
  __syncthreads();

  // ---- stage 2: GRU ----
  short8_t xh[4], hh[4];
  {
    int row = row0l + cl;
    const float* hp = Hin + (size_t)(row0g + cl) * 128;
#pragma unroll
    for (int kk = 0; kk < 4; ++kk) {
      int ad = (row * 256 + kk * 64 + kg * 16) ^ ((row & 7) << 4);
      xh[kk] = *(const short8_t*)((const char*)mid + ad);
      load_afrag(hp + kk * 32 + kg * 8, hh[kk]);
    }
  }
#define GLOAD(P, CT) *(const short8_t*)((P) + (((size_t)(CT) * 4 + kk) * 64 + lane) * 8)
  for (int ct = 0; ct < 8; ++ct) {
    f32x4_t aXr = (f32x4_t){0.f, 0.f, 0.f, 0.f}, aXz = aXr, aXn = aXr;
    f32x4_t aHr = aXr, aHz = aXr, aHn = aXr;
#pragma unroll
    for (int kk = 0; kk < 4; ++kk) {
      short8_t b_h;
      b_h = GLOAD(WiP, ct);      MFMA(aXr, xh[kk], b_h);
      b_h = GLOAD(WiP, ct + 8);  MFMA(aXz, xh[kk], b_h);
      b_h = GLOAD(WiP, ct + 16); MFMA(aXn, xh[kk], b_h);
      b_h = GLOAD(WhP, ct);      MFMA(aHr, hh[kk], b_h);
      b_h = GLOAD(WhP, ct + 8);  MFMA(aHz, hh[kk], b_h);
      b_h = GLOAD(WhP, ct + 16); MFMA(aHn, hh[kk], b_h);
    }
    int col = ct * 16 + cl;
    float bir = gbi[col], biz = gbi[128 + col], bin = gbi[256 + col];
    float bhr = gbh[col], bhz = gbh[128 + col], bhn = gbh[256 + col];
#pragma unroll
    for (int j = 0; j < 4; ++j) {
      int row = row0g + kg * 4 + j;
      float rg = fast_sigmoid(aXr[j] + aHr[j] + bir + bhr);
      float zg = fast_sigmoid(aXz[j] + aHz[j] + biz + bhz);
      float ng = fast_tanh(aXn[j] + bin + rg * (aHn[j] + bhn));
      float hv = Hin[(size_t)row * 128 + col];
      Hout[(size_t)row * 128 + col] = (1.f - zg) * ng + zg * hv;
    }
  }
#undef GLOAD
}

// ---------------- fused attention: MFMA proj + MFMA scores + parallel softmax ------------
__global__ __launch_bounds__(256) void attn_fused_kernel(
    const float* __restrict__ Hh, const short* __restrict__ QKp,
    float* __restrict__ attn_out, short* __restrict__ si) {
  __shared__ short qkb[2][32 * 128];   // 2 x 8 KB, 256B rows, XOR-swizzled
  __shared__ float p[32][33];
  __shared__ float a2[32][33];
  const int b = blockIdx.x;
  const int tid = threadIdx.x;
  const int wave = tid >> 6, lane = tid & 63;
  const int cl = lane & 15, kg = lane >> 4;

  // ---- proj: q/k = h @ Wq/Wk -> bf16 LDS ----
  {
    short8_t ahf[2][4];
#pragma unroll
    for (int m = 0; m < 2; ++m) {
      const float* ap = Hh + (size_t)(b * 32 + m * 16 + cl) * 128;
#pragma unroll
      for (int kk = 0; kk < 4; ++kk) load_afrag(ap + kk * 32 + kg * 8, ahf[m][kk]);
    }
    const int proj = wave >> 1;
    const short* Wbase = QKp + (size_t)proj * 16384;
    short* dst = &qkb[proj][0];
#pragma unroll
    for (int ct4 = 0; ct4 < 4; ++ct4) {
      int ct = (wave & 1) * 4 + ct4;
      f32x4_t a0 = (f32x4_t){0.f, 0.f, 0.f, 0.f};
      f32x4_t a1 = (f32x4_t){0.f, 0.f, 0.f, 0.f};
#pragma unroll
      for (int kk = 0; kk < 4; ++kk) {
        short8_t b_h = *(const short8_t*)(Wbase + (((size_t)ct * 4 + kk) * 64 + lane) * 8);
        MFMA(a0, ahf[0][kk], b_h);
        MFMA(a1, ahf[1][kk], b_h);
      }
      int col = ct * 16 + cl;
      int c2hi = (col * 2) & ~15, c2lo = (col * 2) & 15;
#pragma unroll
      for (int j = 0; j < 4; ++j) {
        int r0 = kg * 4 + j;
        int r1 = 16 + kg * 4 + j;
        int ad0 = ((r0 * 256 + c2hi) ^ ((r0 & 7) << 4)) + c2lo;
        int ad1 = ((r1 * 256 + c2hi) ^ ((r1 & 7) << 4)) + c2lo;
        *(short*)((char*)dst + ad0) = f2bf(a0[j]);
        *(short*)((char*)dst + ad1) = f2bf(a1[j]);
      }
    }
  }
  __syncthreads();

  // ---- scores via MFMA: wave computes tile (mi, nj) ----
  {
    const int mi = wave >> 1, nj = wave & 1;
    short8_t qf[4], kf[4];
    int rq = mi * 16 + cl, rk = nj * 16 + cl;
#pragma unroll
    for (int kk = 0; kk < 4; ++kk) {
      int adq = (rq * 256 + kk * 64 + kg * 16) ^ ((rq & 7) << 4);
      int adk = (rk * 256 + kk * 64 + kg * 16) ^ ((rk & 7) << 4);
      qf[kk] = *(const short8_t*)((const char*)&qkb[0][0] + adq);
      kf[kk] = *(const short8_t*)((const char*)&qkb[1][0] + adk);
    }
    f32x4_t acc = (f32x4_t){0.f, 0.f, 0.f, 0.f};
#pragma unroll
    for (int kk = 0; kk < 4; ++kk) MFMA(acc, qf[kk], kf[kk]);
    const float scale = 0.088388347648318447f;  // 1/sqrt(128)
#pragma unroll
    for (int j = 0; j < 4; ++j) {
      int r = mi * 16 + kg * 4 + j;
      int c = nj * 16 + cl;
      p[r][c] = (r == c) ? -1e9f : acc[j] * scale;
    }
  }
  __syncthreads();

  // ---- softmax: 8 threads per row ----
  {
    int row = tid >> 3, g = tid & 7;
    float v[4];
    float mx = -1e30f;
#pragma unroll
    for (int c0 = 0; c0 < 4; ++c0) {
      v[c0] = p[row][g * 4 + c0];
      mx = fmaxf(mx, v[c0]);
    }
#pragma unroll
    for (int off = 1; off < 8; off <<= 1) mx = fmaxf(mx, __shfl_xor(mx, off, 64));
    float s = 0.f;
#pragma unroll
    for (int c0 = 0; c0 < 4; ++c0) {
      v[c0] = __expf(v[c0] - mx);
      s += v[c0];
    }
#pragma unroll
    for (int off = 1; off < 8; off <<= 1) s += __shfl_xor(s, off, 64);
    float inv = frcp_(s);
#pragma unroll
    for (int c0 = 0; c0 < 4; ++c0) p[row][g * 4 + c0] = v[c0] * inv;
  }
  __syncthreads();

  // ---- symmetrize + attn_out ----
#pragma unroll
  for (int tI = 0; tI < 4; ++tI) {
    int t = tid + tI * 256;
    int i = t >> 5, j = t & 31;
    float v = (i == j) ? 0.f : 0.5f * (p[i][j] + p[j][i]);
    a2[i][j] = v;
    attn_out[(size_t)b * 1024 + t] = v;
  }
  __syncthreads();

  // ---- struct input: 8 threads per row ----
  {
    int row = tid >> 3, g = tid & 7;
    float vv[4];
    float d = 0.f, en = 0.f;
#pragma unroll
    for (int c0 = 0; c0 < 4; ++c0) {
      float v = a2[row][g * 4 + c0];
      vv[c0] = v;
      d += v;
      float c = fmaxf(v, 1e-8f);
      en -= c * __logf(c);
    }
#pragma unroll
    for (int off = 1; off < 8; off <<= 1) {
      d += __shfl_xor(d, off, 64);
      en += __shfl_xor(en, off, 64);
    }
    short* srow = si + ((size_t)b * 32 + row) * 64;
#pragma unroll
    for (int c0 = 0; c0 < 4; ++c0) srow[g * 4 + c0] = f2bf(vv[c0]);
    if (g == 0) {
      srow[32] = f2bf(d);
      srow[33] = f2bf(en);
    }
    for (int z = 34 + g; z < 64; z += 8) srow[z] = 0;
  }
}

// ---------------- fused se1+se2+group+gd1+gd2: 64-row blocks, 1 m-frag/wave (grid 1024) ----
__global__ __launch_bounds__(256, 4) void se_gd_kernel(
    const short* __restrict__ SI,
    const short* __restrict__ Se1p, const float* __restrict__ se1b,
    const short* __restrict__ Se2p, const float* __restrict__ se2b,
    const float* __restrict__ ga_w, const float* __restrict__ ga_b,
    const float* __restrict__ gemb, float* __restrict__ probs,
    const short* __restrict__ Gd1p, const float* __restrict__ gd1b,
    const short* __restrict__ Gd2p, const float* __restrict__ gd2b,
    float* __restrict__ gs_out, short* __restrict__ gs16) {
  __shared__ short mid[64 * 256];   // 32 KB, 512B rows, XOR-swizzled
  const int tid = threadIdx.x;
  const int wave = tid >> 6, lane = tid & 63;
  const int cl = lane & 15, kg = lane >> 4;
  const int row0g = blockIdx.x * 64;
  const int row0l = wave * 16;

  // ===== se1 -> mid =====
  {
    short8_t ah1[2];
    {
      const short* ap = SI + (size_t)(row0g + row0l + cl) * 64;
#pragma unroll
      for (int kk = 0; kk < 2; ++kk)
        ah1[kk] = *(const short8_t*)(ap + kk * 32 + kg * 8);
    }
    for (int ct = 0; ct < 16; ++ct) {
      f32x4_t a0 = (f32x4_t){0.f, 0.f, 0.f, 0.f};
#pragma unroll
      for (int kk = 0; kk < 2; ++kk) {
        short8_t b_h = *(const short8_t*)(Se1p + (((size_t)ct * 2 + kk) * 64 + lane) * 8);
        MFMA(a0, ah1[kk], b_h);
      }
      int col = ct * 16 + cl;
      float bv = se1b[col];
      int c2hi = (col * 2) & ~15, c2lo = (col * 2) & 15;
#pragma unroll
      for (int j = 0; j < 4; ++j) {
        float v0 = fmaxf(a0[j] + bv, 0.f);
        int r0 = row0l + kg * 4 + j;
        int ad0 = ((r0 * 512 + c2hi) ^ ((r0 & 7) << 4)) + c2lo;
        *(short*)((char*)mid + ad0) = f2bf(v0);
      }
    }
  }
  __syncthreads();

  // ===== se2 -> sf (back into mid) =====
  {
    short8_t ah2[8];
    {
      int row = row0l + cl;
#pragma unroll
      for (int kk = 0; kk < 8; ++kk) {
        int ad = (row * 512 + kk * 64 + kg * 16) ^ ((row & 7) << 4);
        ah2[kk] = *(const short8_t*)((const char*)mid + ad);
      }
    }
    __syncthreads();  // all mid reads done; region reusable as sf
    for (int ct = 0; ct < 16; ++ct) {
      f32x4_t a0 = (f32x4_t){0.f, 0.f, 0.f, 0.f};
#pragma unroll
      for (int kk = 0; kk < 8; ++kk) {
        short8_t b_h = *(const short8_t*)(Se2p + (((size_t)ct * 8 + kk) * 64 + lane) * 8);
        MFMA(a0, ah2[kk], b_h);
      }
      int col = ct * 16 + cl;
      float bv = se2b[col];
      int c2hi = (col * 2) & ~15, c2lo = (col * 2) & 15;
#pragma unroll
      for (int j = 0; j < 4; ++j) {
        float v0 = fast_tanh(a0[j] + bv);
        int r0 = row0l + kg * 4 + j;
        int ad0 = ((r0 * 512 + c2hi) ^ ((r0 & 7) << 4)) + c2lo;
        *(short*)((char*)mid + ad0) = f2bf(v0);
      }
    }
  }
  __syncthreads();

  // ===== group assign -> probs + t frags =====
  short8_t tfr[8];
  {
    short8_t sfr[8];
    float lg[3] = {};
    {
      int row = row0l + cl;
#pragma unroll
      for (int kk = 0; kk < 8; ++kk) {
        int ad = (row * 512 + kk * 64 + kg * 16) ^ ((row & 7) << 4);
        short8_t s = *(const short8_t*)((const char*)mid + ad);
        sfr[kk] = s;
        int e0 = kk * 32 + kg * 8;
#pragma unroll
        for (int i = 0; i < 8; ++i) {
          float v = bf2f(s[i]);
          lg[0] = fmaf(v, ga_w[(e0 + i) * 3 + 0], lg[0]);
          lg[1] = fmaf(v, ga_w[(e0 + i) * 3 + 1], lg[1]);
          lg[2] = fmaf(v, ga_w[(e0 + i) * 3 + 2], lg[2]);
        }
      }
    }
#pragma unroll
    for (int g = 0; g < 3; ++g) {
      lg[g] += __shfl_xor(lg[g], 16, 64);
      lg[g] += __shfl_xor(lg[g], 32, 64);
    }
    float l0 = lg[0] + ga_b[0], l1 = lg[1] + ga_b[1], l2 = lg[2] + ga_b[2];
    float mx = fmaxf(l0, fmaxf(l1, l2));
    float e0 = __expf(l0 - mx), e1 = __expf(l1 - mx), e2 = __expf(l2 - mx);
    float inv = frcp_(e0 + e1 + e2);
    float p0 = e0 * inv, p1 = e1 * inv, p2 = e2 * inv;
    if (kg == 0) {
      size_t r = (size_t)(row0g + row0l + cl) * 3;
      probs[r + 0] = p0;
      probs[r + 1] = p1;
      probs[r + 2] = p2;
    }
#pragma unroll
    for (int kk = 0; kk < 8; ++kk) {
      int e0i = kk * 32 + kg * 8;
      short8_t tf;
#pragma unroll
      for (int i = 0; i < 8; ++i) {
        float tv = bf2f(sfr[kk][i]) + p0 * gemb[e0i + i] +
                   p1 * gemb[256 + e0i + i] + p2 * gemb[512 + e0i + i];
        tf[i] = f2bf(tv);
      }
      tfr[kk] = tf;
    }
  }
  __syncthreads();  // all sf reads done; mid region reusable

  // ===== gd1 -> mid, gd2 -> gs_out f32 + gs16 bf16 =====
  for (int ct = 0; ct < 16; ++ct) {
    f32x4_t a0 = (f32x4_t){0.f, 0.f, 0.f, 0.f};
#pragma unroll
    for (int kk = 0; kk < 8; ++kk) {
      short8_t b_h = *(const short8_t*)(Gd1p + (((size_t)ct * 8 + kk) * 64 + lane) * 8);
      MFMA(a0, tfr[kk], b_h);
    }
    int col = ct * 16 + cl;
    float bv = gd1b[col];
    int c2hi = (col * 2) & ~15, c2lo = (col * 2) & 15;
#pragma unroll
    for (int j = 0; j < 4; ++j) {
      float v0 = fmaxf(a0[j] + bv, 0.f);
      int r0 = row0l + kg * 4 + j;
      int ad0 = ((r0 * 512 + c2hi) ^ ((r0 & 7) << 4)) + c2lo;
      *(short*)((char*)mid + ad0) = f2bf(v0);
    }
  }
  __syncthreads();
  {
    short8_t ah2[8];
    {
      int row = row0l + cl;
#pragma unroll
      for (int kk = 0; kk < 8; ++kk) {
        int ad = (row * 512 + kk * 64 + kg * 16) ^ ((row & 7) << 4);
        ah2[kk] = *(const short8_t*)((const char*)mid + ad);
      }
    }
    for (int ct = 0; ct < 16; ++ct) {
      f32x4_t a0 = (f32x4_t){0.f, 0.f, 0.f, 0.f};
#pragma unroll
      for (int kk = 0; kk < 8; ++kk) {
        short8_t b_h = *(const short8_t*)(Gd2p + (((size_t)ct * 8 + kk) * 64 + lane) * 8);
        MFMA(a0, ah2[kk], b_h);
      }
      int col = ct * 16 + cl;
      float bv = gd2b[col];
#pragma unroll
      for (int j = 0; j < 4; ++j) {
        float v0 = fast_tanh(a0[j] + bv);
        size_t r0 = (size_t)(row0g + row0l + kg * 4 + j) * 256 + col;
        gs_out[r0] = v0;
        gs16[r0] = f2bf(v0);
      }
    }
  }
}

// ---------------- MFMA hypernet q v11: v10 + global_load_lds staging + bias-in-C -------
// Half-split (grid 512), col-major h LDS, ct-pair dbuf staged via async DMA.
__global__ __launch_bounds__(256, 2) void hyper_q_v11_kernel(
    const short* __restrict__ GS16, const float* __restrict__ Hh,
    const short* __restrict__ Wp, const float* __restrict__ hwb,
    float* __restrict__ Qpart) {
  __shared__ short Bh[2][8192];        // 32 KB: two ct-pair buffers
  __shared__ short h_lds[4][64][68];   // 34 KB, col-major: [wave][col][row], stride 68
  const int tid = threadIdx.x;
  const int wave = tid >> 6, lane = tid & 63;
  const int cl = lane & 15, kg = lane >> 4;
  const int half = blockIdx.x >> 8;
  const int wrow = (blockIdx.x & 255) * 256 + wave * 64;
  const int ct_base = half * 128;

  // ---- stage h block col-major: lane owns row `lane` ----
  {
    const float* hp = Hh + (size_t)(wrow + lane) * 128 + half * 64;
#pragma unroll
    for (int c = 0; c < 64; c += 4) {
      float4 u = *(const float4*)(hp + c);
      h_lds[wave][c + 0][lane] = f2bf(u.x);
      h_lds[wave][c + 1][lane] = f2bf(u.y);
      h_lds[wave][c + 2][lane] = f2bf(u.z);
      h_lds[wave][c + 3][lane] = f2bf(u.w);
    }
  }

  // ---- A (gs bf16) -> registers: 4 m-frags x 8 kk ----
  short8_t ah[4][8];
#pragma unroll
  for (int m = 0; m < 4; ++m) {
    const short* ap = GS16 + (size_t)(wrow + m * 16 + cl) * 256;
#pragma unroll
    for (int kk = 0; kk < 8; ++kk) ah[m][kk] = *(const short8_t*)(ap + kk * 32 + kg * 8);
  }

  // ---- prologue: DMA ct pair {base, base+1} into buf 0 ----
  {
    const short* wp0 = Wp + (size_t)ct_base * 4096;
#pragma unroll
    for (int k = 0; k < 4; ++k)
      async_cp16(wp0 + k * 2048 + tid * 8, &Bh[0][k * 2048 + tid * 8]);
  }
  __syncthreads();

  float qf[4][2][4] = {};
  int cur = 0;

#define COMPUTE_CT(BUFP, OH, WB)                                               \
  {                                                                            \
    f32x4_t acc[4];                                                            \
    _Pragma("unroll")                                                          \
    for (int m = 0; m < 4; ++m) acc[m] = (f32x4_t){(WB), (WB), (WB), (WB)};    \
    _Pragma("unroll")                                                          \
    for (int kk = 0; kk < 8; ++kk) {                                           \
      short8_t b_h = *(const short8_t*)((BUFP) + ((OH) * 4096 + (kk * 64 + lane) * 8)); \
      _Pragma("unroll")                                                        \
      for (int m = 0; m < 4; ++m) MFMA(acc[m], ah[m][kk], b_h);                \
    }                                                                          \
    _Pragma("unroll")                                                          \
    for (int m = 0; m < 4; ++m)                                                \
      _Pragma("unroll")                                                        \
      for (int j = 0; j < 4; ++j)                                              \
        qf[m][OH][j] = fmaf(hc[m * 4 + j], acc[m][j], qf[m][OH][j]);           \
  }

  for (int t2 = 0; t2 < 64; ++t2) {
    const int ct0 = ct_base + t2 * 2;
    // issue DMA for next ct pair into the other buffer (drained by the barrier below)
    if (t2 < 63) {
      const short* wpn = Wp + (size_t)(ct0 + 2) * 4096;
      short* bufn = &Bh[cur ^ 1][0];
#pragma unroll
      for (int k = 0; k < 4; ++k)
        async_cp16(wpn + k * 2048 + tid * 8, bufn + k * 2048 + tid * 8);
    }
    // h column t2: 4 broadcast b64 reads (per m, 4 consecutive rows)
    float hc[16];
#pragma unroll
    for (int m = 0; m < 4; ++m) {
      short4_t v4 = *(const short4_t*)&h_lds[wave][t2][m * 16 + kg * 4];
#pragma unroll
      for (int j = 0; j < 4; ++j) hc[m * 4 + j] = bf2f(v4[j]);
    }
    float wb0 = hwb[ct0 * 16 + cl];
    float wb1 = hwb[(ct0 + 1) * 16 + cl];
    const short* bufp = &Bh[cur][0];
    COMPUTE_CT(bufp, 0, wb0)
    COMPUTE_CT(bufp, 1, wb1)
    __syncthreads();
    cur ^= 1;
  }
#undef COMPUTE_CT

  // ---- half 0 adds fc2_b = gs @ hb_w via packed chunks 256/257 (direct L2) ----
  if (half == 0) {
#pragma unroll
    for (int oh = 0; oh < 2; ++oh) {
      f32x4_t bacc[4];
#pragma unroll
      for (int m = 0; m < 4; ++m) bacc[m] = (f32x4_t){0.f, 0.f, 0.f, 0.f};
#pragma unroll
      for (int kk = 0; kk < 8; ++kk) {
        short8_t b_h = *(const short8_t*)(Wp + (((size_t)(256 + oh) * 8 + kk) * 64 + lane) * 8);
#pragma unroll
        for (int m = 0; m < 4; ++m) MFMA(bacc[m], ah[m][kk], b_h);
      }
#pragma unroll
      for (int m = 0; m < 4; ++m)
#pragma unroll
        for (int j = 0; j < 4; ++j) qf[m][oh][j] += bacc[m][j];
    }
  }

  // ---- write partial q ----
  float* qp = Qpart + (size_t)half * 2097152;
#pragma unroll
  for (int m = 0; m < 4; ++m)
#pragma unroll
    for (int j = 0; j < 4; ++j) {
      const size_t r = (size_t)(wrow + m * 16 + kg * 4 + j) * 32;
      qp[r + cl] = qf[m][0][j];
      qp[r + 16 + cl] = qf[m][1][j];
    }
}

// ---------------- combine: q = qpart0 + qpart1 + hb_b ----------------
__global__ __launch_bounds__(256) void qcombine_kernel(
    const float* __restrict__ Qpart, const float* __restrict__ hbb,
    float* __restrict__ Qout) {
  int i = blockIdx.x * 256 + threadIdx.x;  // 524288 float4s
  float4 a = ((const float4*)Qpart)[i];
  float4 b = ((const float4*)(Qpart + 2097152))[i];
  float4 e = ((const float4*)hbb)[i & 7];
  ((float4*)Qout)[i] = make_float4(a.x + b.x + e.x, a.y + b.y + e.y,
                                   a.z + b.z + e.z, a.w + b.w + e.w);
}

extern "C" void kernel_launch(void* const* d_in, const int* in_sizes, int n_in,
                              void* d_out, int out_size, void* d_ws, size_t ws_size,
                              hipStream_t stream) {
  const float* inputs   = (const float*)d_in[0];
  const float* hidden   = (const float*)d_in[1];
  const float* fc1_w    = (const float*)d_in[2];
  const float* fc1_b    = (const float*)d_in[3];
  const float* gru_wi   = (const float*)d_in[4];
  const float* gru_wh   = (const float*)d_in[5];
  const float* gru_bi   = (const float*)d_in[6];
  const float* gru_bh   = (const float*)d_in[7];
  const float* attn_q_w = (const float*)d_in[8];
  const float* attn_k_w = (const float*)d_in[9];
  const float* se1_w    = (const float*)d_in[10];
  const float* se1_b    = (const float*)d_in[11];
  const float* se2_w    = (const float*)d_in[12];
  const float* se2_b    = (const float*)d_in[13];
  const float* ga_w     = (const float*)d_in[14];
  const float* ga_b     = (const float*)d_in[15];
  const float* gemb     = (const float*)d_in[16];
  const float* gd1_w    = (const float*)d_in[17];
  const float* gd1_b    = (const float*)d_in[18];
  const float* gd2_w    = (const float*)d_in[19];
  const float* gd2_b    = (const float*)d_in[20];
  const float* hb_w     = (const float*)d_in[21];
  const float* hb_b     = (const float*)d_in[22];
  const float* hw_w     = (const float*)d_in[23];
  const float* hw_b     = (const float*)d_in[24];

  float* out = (float*)d_out;
  float* q_out     = out;              // [R,32]
  float* h_out     = out + 2097152;    // [R,128]
  float* gs_out    = out + 10485760;   // [R,256]
  float* probs_out = out + 27262976;   // [R,3]
  float* attn_out  = out + 27459584;   // [B,32,32]

  // workspace layout (bytes), all regions disjoint:
  //   [0,16M):   qpart f32 [2][R,32]
  //   [16M,24M): si bf16 [R,64]
  //   [24M,56M): gs16 bf16 [R,256]
  //   [56M,+2.9M): packs
  char* wsb = (char*)d_ws;
  float* qpart = (float*)wsb;
  short* si   = (short*)(wsb + (size_t)16 * 1024 * 1024);
  short* gs16 = (short*)(wsb + (size_t)24 * 1024 * 1024);
  short* P    = (short*)(wsb + (size_t)56 * 1024 * 1024);

  // pack offsets (shorts); chunk = KK*512 shorts
  const size_t o_hw  = 0;        // K=256 KK=8, N=4096 (+hb chunks 256..257)
  const size_t o_hb  = 1048576;
  const size_t o_fc1 = 1056768;
  const size_t o_wi  = 1077248;
  const size_t o_wh  = 1126400;
  const size_t o_qkq = 1175552;
  const size_t o_qkk = 1191936;  // must be o_qkq + 16384 (attn assumes contiguity)
  const size_t o_se1 = 1208320;
  const size_t o_se2 = 1224704;
  const size_t o_gd1 = 1290240;
  const size_t o_gd2 = 1355776;

  PackArgs pa;
  pa.s[0]  = {hw_w,     256, 4096, 8, 0,    4096, o_hw};
  pa.s[1]  = {hb_w,     256, 32,   8, 4096, 32,   o_hb};
  pa.s[2]  = {fc1_w,    160, 128,  5, 4128, 80,   o_fc1};
  pa.s[3]  = {gru_wi,   128, 384,  4, 4208, 192,  o_wi};
  pa.s[4]  = {gru_wh,   128, 384,  4, 4400, 192,  o_wh};
  pa.s[5]  = {attn_q_w, 128, 128,  4, 4592, 64,   o_qkq};
  pa.s[6]  = {attn_k_w, 128, 128,  4, 4656, 64,   o_qkk};
  pa.s[7]  = {se1_w,    34,  256,  2, 4720, 64,   o_se1};
  pa.s[8]  = {se2_w,    256, 256,  8, 4784, 256,  o_se2};
  pa.s[9]  = {gd1_w,    256, 256,  8, 5040, 256,  o_gd1};
  pa.s[10] = {gd2_w,    256, 256,  8, 5296, 256,  o_gd2};

  dim3 blk(256);
  // 0) pack ALL weights in one launch
  pack_all_kernel<<<5552, blk, 0, stream>>>(pa, P);
  // 1) h = GRUCell(relu(inputs@fc1+b), hidden) -> h_out f32  (64-row blocks)
  gru_fused_kernel<<<1024, blk, 0, stream>>>(inputs, hidden, P + o_fc1, fc1_b,
                                             P + o_wi, P + o_wh, gru_bi, gru_bh, h_out);
  // 2) attention (standalone, 2048 blocks) -> attn_out f32 + si bf16
  attn_fused_kernel<<<2048, blk, 0, stream>>>(h_out, P + o_qkq, attn_out, si);
  // 3) se1+se2+group+gd1+gd2 fused (64-row blocks) -> probs + gs_out f32 + gs16 bf16
  se_gd_kernel<<<1024, blk, 0, stream>>>(si, P + o_se1, se1_b, P + o_se2, se2_b,
                                         ga_w, ga_b, gemb, probs_out,
                                         P + o_gd1, gd1_b, P + o_gd2, gd2_b,
                                         gs_out, gs16);
  // 4) q partials: half-split, col-major h LDS, async-DMA ct-pair dbuf
  hyper_q_v11_kernel<<<dim3(512), blk, 0, stream>>>(gs16, h_out, P + o_hw, hw_b, qpart);
  // 5) q = qpart0 + qpart1 + hb_b
  qcombine_kernel<<<2048, blk, 0, stream>>>(qpart, hb_b, q_out);
}

// Round 17
// 260.134 us; speedup vs baseline: 1.0201x; 1.0201x over previous
//
#include <hip/hip_runtime.h>
#include <math.h>

// B=2048, A=32 -> R=65536 rows. E_IN=160, H=128, HE=256, NACT=32, G=3, TAU=1.
#define R_TOTAL 65536

typedef __attribute__((ext_vector_type(8))) short short8_t;
typedef __attribute__((ext_vector_type(4))) short short4_t;
typedef __attribute__((ext_vector_type(4))) float f32x4_t;

__device__ __forceinline__ float frcp_(float x) { return __builtin_amdgcn_rcpf(x); }
__device__ __forceinline__ float fast_sigmoid(float x) { return frcp_(1.f + __expf(-x)); }
__device__ __forceinline__ float fast_tanh(float x) {
  float xc = fminf(fmaxf(x, -15.f), 15.f);
  float t = __expf(2.f * xc);
  return (t - 1.f) * frcp_(t + 1.f);
}

__device__ __forceinline__ short f2bf(float x) {
  unsigned u = __float_as_uint(x);
  u += 0x7fff + ((u >> 16) & 1);   // round-to-nearest-even
  return (short)(u >> 16);
}
__device__ __forceinline__ float bf2f(short s) {
  return __uint_as_float(((unsigned)(unsigned short)s) << 16);
}

// async global->LDS 16B per lane (dest must be wave-uniform base + lane*16)
__device__ __forceinline__ void async_cp16(const short* gsrc, short* ldst) {
  __builtin_amdgcn_global_load_lds(
      (const __attribute__((address_space(1))) void*)gsrc,
      (__attribute__((address_space(3))) void*)ldst, 16, 0, 0);
}

// Load 8 consecutive floats -> bf16 fragment (RNE).
__device__ __forceinline__ void load_afrag(const float* p, short8_t& h) {
  float4 u0 = *(const float4*)p;
  float4 u1 = *(const float4*)(p + 4);
  float v[8] = {u0.x, u0.y, u0.z, u0.w, u1.x, u1.y, u1.z, u1.w};
#pragma unroll
  for (int i = 0; i < 8; ++i) h[i] = f2bf(v[i]);
}

#define MFMA(ACC, A, B) ACC = __builtin_amdgcn_mfma_f32_16x16x32_bf16(A, B, ACC, 0, 0, 0)

// ---------------- fused fragment pack: all weights in one launch ----------------
struct PackSeg {
  const float* W;
  int Ksrc, N, KK, blk0, nblk;
  size_t off;
};
struct PackArgs { PackSeg s[11]; };

__global__ __launch_bounds__(256) void pack_all_kernel(PackArgs a, short* __restrict__ P) {
  const int b = blockIdx.x;
  PackSeg seg = a.s[0];
#pragma unroll
  for (int i = 1; i < 11; ++i)
    if (b >= a.s[i].blk0) seg = a.s[i];
  int p = (b - seg.blk0) * 256 + threadIdx.x;
  int i = p & 7, lane = (p >> 3) & 63, kk = (p >> 9) % seg.KK, ct = p / (seg.KK * 512);
  int e = kk * 32 + (lane >> 4) * 8 + i;
  int c = ct * 16 + (lane & 15);
  float w = (e < seg.Ksrc) ? seg.W[(size_t)e * seg.N + c] : 0.f;
  P[seg.off + p] = f2bf(w);
}

// ---------------- fused fc1 + GRU: 64-row blocks, 1 m-frag/wave (grid 1024) ----------------
// Dual-writes h: f32 to Hout (module output) + bf16 to H16 (downstream consumers).
__global__ __launch_bounds__(256, 4) void gru_fused_kernel(
    const float* __restrict__ inputs, const float* __restrict__ Hin,
    const short* __restrict__ Fc1p, const float* __restrict__ fc1b,
    const short* __restrict__ WiP, const short* __restrict__ WhP,
    const float* __restrict__ gbi, const float* __restrict__ gbh,
    float* __restrict__ Hout, short* __restrict__ H16) {
  __shared__ short mid[64 * 128];   // 16 KB, 256B rows, XOR-swizzled
  const int tid = threadIdx.x;
  const int wave = tid >> 6, lane = tid & 63;
  const int cl = lane & 15, kg = lane >> 4;
  const int row0g = blockIdx.x * 64 + wave * 16;
  const int row0l = wave * 16;

  // ---- stage 1: x = relu(inputs @ fc1 + b) ----
  {
    short8_t ah1[5];
    {
      const float* ap = inputs + (size_t)(row0g + cl) * 160;
#pragma unroll
      for (int kk = 0; kk < 5; ++kk) load_afrag(ap + kk * 32 + kg * 8, ah1[kk]);
    }
    for (int ct = 0; ct < 8; ++ct) {
      f32x4_t a0 = (f32x4_t){0.f, 0.f, 0.f, 0.f};
#pragma unroll
      for (int kk = 0; kk < 5; ++kk) {
        short8_t b_h = *(const short8_t*)(Fc1p + (((size_t)ct * 5 + kk) * 64 + lane) * 8);
        MFMA(a0, ah1[kk], b_h);
      }
      int col = ct * 16 + cl;
      float bv = fc1b[col];
      int c2hi = (col * 2) & ~15, c2lo = (col * 2) & 15;
#pragma unroll
      for (int j = 0; j < 4; ++j) {
        float v0 = fmaxf(a0[j] + bv, 0.f);
        int r0 = row0l + kg * 4 + j;
        int ad0 = ((r0 * 256 + c2hi) ^ ((r0 & 7) << 4)) + c2lo;
        *(short*)((char*)mid + ad0) = f2bf(v0);
      }
    }
  }
  __syncthreads();

  // ---- stage 2: GRU ----
  short8_t xh[4], hh[4];
  {
    int row = row0l + cl;
    const float* hp = Hin + (size_t)(row0g + cl) * 128;
#pragma unroll
    for (int kk = 0; kk < 4; ++kk) {
      int ad = (row * 256 + kk * 64 + kg * 16) ^ ((row & 7) << 4);
      xh[kk] = *(const short8_t*)((const char*)mid + ad);
      load_afrag(hp + kk * 32 + kg * 8, hh[kk]);
    }
  }
#define GLOAD(P, CT) *(const short8_t*)((P) + (((size_t)(CT) * 4 + kk) * 64 + lane) * 8)
  for (int ct = 0; ct < 8; ++ct) {
    f32x4_t aXr = (f32x4_t){0.f, 0.f, 0.f, 0.f}, aXz = aXr, aXn = aXr;
    f32x4_t aHr = aXr, aHz = aXr, aHn = aXr;
#pragma unroll
    for (int kk = 0; kk < 4; ++kk) {
      short8_t b_h;
      b_h = GLOAD(WiP, ct);      MFMA(aXr, xh[kk], b_h);
      b_h = GLOAD(WiP, ct + 8);  MFMA(aXz, xh[kk], b_h);
      b_h = GLOAD(WiP, ct + 16); MFMA(aXn, xh[kk], b_h);
      b_h = GLOAD(WhP, ct);      MFMA(aHr, hh[kk], b_h);
      b_h = GLOAD(WhP, ct + 8);  MFMA(aHz, hh[kk], b_h);
      b_h = GLOAD(WhP, ct + 16); MFMA(aHn, hh[kk], b_h);
    }
    int col = ct * 16 + cl;
    float bir = gbi[col], biz = gbi[128 + col], bin = gbi[256 + col];
    float bhr = gbh[col], bhz = gbh[128 + col], bhn = gbh[256 + col];
#pragma unroll
    for (int j = 0; j < 4; ++j) {
      int row = row0g + kg * 4 + j;
      float rg = fast_sigmoid(aXr[j] + aHr[j] + bir + bhr);
      float zg = fast_sigmoid(aXz[j] + aHz[j] + biz + bhz);
      float ng = fast_tanh(aXn[j] + bin + rg * (aHn[j] + bhn));
      float hv = Hin[(size_t)row * 128 + col];
      float ho = (1.f - zg) * ng + zg * hv;
      Hout[(size_t)row * 128 + col] = ho;
      H16[(size_t)row * 128 + col] = f2bf(ho);
    }
  }
#undef GLOAD
}

// ---------------- fused attention v3: h16 input, fused symmetrize/struct phase ----------
__global__ __launch_bounds__(256) void attn_fused_kernel(
    const short* __restrict__ H16, const short* __restrict__ QKp,
    float* __restrict__ attn_out, short* __restrict__ si) {
  __shared__ short qkb[2][32 * 128];   // 2 x 8 KB, 256B rows, XOR-swizzled
  __shared__ float p[32][33];
  const int b = blockIdx.x;
  const int tid = threadIdx.x;
  const int wave = tid >> 6, lane = tid & 63;
  const int cl = lane & 15, kg = lane >> 4;

  // ---- proj: q/k = h @ Wq/Wk -> bf16 LDS (A-frags direct from h16) ----
  {
    short8_t ahf[2][4];
#pragma unroll
    for (int m = 0; m < 2; ++m) {
      const short* ap = H16 + (size_t)(b * 32 + m * 16 + cl) * 128;
#pragma unroll
      for (int kk = 0; kk < 4; ++kk)
        ahf[m][kk] = *(const short8_t*)(ap + kk * 32 + kg * 8);
    }
    const int proj = wave >> 1;
    const short* Wbase = QKp + (size_t)proj * 16384;
    short* dst = &qkb[proj][0];
#pragma unroll
    for (int ct4 = 0; ct4 < 4; ++ct4) {
      int ct = (wave & 1) * 4 + ct4;
      f32x4_t a0 = (f32x4_t){0.f, 0.f, 0.f, 0.f};
      f32x4_t a1 = (f32x4_t){0.f, 0.f, 0.f, 0.f};
#pragma unroll
      for (int kk = 0; kk < 4; ++kk) {
        short8_t b_h = *(const short8_t*)(Wbase + (((size_t)ct * 4 + kk) * 64 + lane) * 8);
        MFMA(a0, ahf[0][kk], b_h);
        MFMA(a1, ahf[1][kk], b_h);
      }
      int col = ct * 16 + cl;
      int c2hi = (col * 2) & ~15, c2lo = (col * 2) & 15;
#pragma unroll
      for (int j = 0; j < 4; ++j) {
        int r0 = kg * 4 + j;
        int r1 = 16 + kg * 4 + j;
        int ad0 = ((r0 * 256 + c2hi) ^ ((r0 & 7) << 4)) + c2lo;
        int ad1 = ((r1 * 256 + c2hi) ^ ((r1 & 7) << 4)) + c2lo;
        *(short*)((char*)dst + ad0) = f2bf(a0[j]);
        *(short*)((char*)dst + ad1) = f2bf(a1[j]);
      }
    }
  }
  __syncthreads();

  // ---- scores via MFMA: wave computes tile (mi, nj) ----
  {
    const int mi = wave >> 1, nj = wave & 1;
    short8_t qf[4], kf[4];
    int rq = mi * 16 + cl, rk = nj * 16 + cl;
#pragma unroll
    for (int kk = 0; kk < 4; ++kk) {
      int adq = (rq * 256 + kk * 64 + kg * 16) ^ ((rq & 7) << 4);
      int adk = (rk * 256 + kk * 64 + kg * 16) ^ ((rk & 7) << 4);
      qf[kk] = *(const short8_t*)((const char*)&qkb[0][0] + adq);
      kf[kk] = *(const short8_t*)((const char*)&qkb[1][0] + adk);
    }
    f32x4_t acc = (f32x4_t){0.f, 0.f, 0.f, 0.f};
#pragma unroll
    for (int kk = 0; kk < 4; ++kk) MFMA(acc, qf[kk], kf[kk]);
    const float scale = 0.088388347648318447f;  // 1/sqrt(128)
#pragma unroll
    for (int j = 0; j < 4; ++j) {
      int r = mi * 16 + kg * 4 + j;
      int c = nj * 16 + cl;
      p[r][c] = (r == c) ? -1e9f : acc[j] * scale;
    }
  }
  __syncthreads();

  // ---- softmax: 8 threads per row ----
  {
    int row = tid >> 3, g = tid & 7;
    float v[4];
    float mx = -1e30f;
#pragma unroll
    for (int c0 = 0; c0 < 4; ++c0) {
      v[c0] = p[row][g * 4 + c0];
      mx = fmaxf(mx, v[c0]);
    }
#pragma unroll
    for (int off = 1; off < 8; off <<= 1) mx = fmaxf(mx, __shfl_xor(mx, off, 64));
    float s = 0.f;
#pragma unroll
    for (int c0 = 0; c0 < 4; ++c0) {
      v[c0] = __expf(v[c0] - mx);
      s += v[c0];
    }
#pragma unroll
    for (int off = 1; off < 8; off <<= 1) s += __shfl_xor(s, off, 64);
    float inv = frcp_(s);
#pragma unroll
    for (int c0 = 0; c0 < 4; ++c0) p[row][g * 4 + c0] = v[c0] * inv;
  }
  __syncthreads();

  // ---- fused symmetrize + attn_out + struct input ----
  {
    int row = tid >> 3, g = tid & 7;
    float vv[4];
    float d = 0.f, en = 0.f;
#pragma unroll
    for (int c0 = 0; c0 < 4; ++c0) {
      int c = g * 4 + c0;
      float v = (row == c) ? 0.f : 0.5f * (p[row][c] + p[c][row]);
      vv[c0] = v;
      d += v;
      float cc = fmaxf(v, 1e-8f);
      en -= cc * __logf(cc);
      attn_out[(size_t)b * 1024 + row * 32 + c] = v;
    }
#pragma unroll
    for (int off = 1; off < 8; off <<= 1) {
      d += __shfl_xor(d, off, 64);
      en += __shfl_xor(en, off, 64);
    }
    short* srow = si + ((size_t)b * 32 + row) * 64;
#pragma unroll
    for (int c0 = 0; c0 < 4; ++c0) srow[g * 4 + c0] = f2bf(vv[c0]);
    if (g == 0) {
      srow[32] = f2bf(d);
      srow[33] = f2bf(en);
    }
    for (int z = 34 + g; z < 64; z += 8) srow[z] = 0;
  }
}

// ---------------- fused se1+se2+group+gd1+gd2: 64-row blocks, 1 m-frag/wave (grid 1024) ----
__global__ __launch_bounds__(256, 4) void se_gd_kernel(
    const short* __restrict__ SI,
    const short* __restrict__ Se1p, const float* __restrict__ se1b,
    const short* __restrict__ Se2p, const float* __restrict__ se2b,
    const float* __restrict__ ga_w, const float* __restrict__ ga_b,
    const float* __restrict__ gemb, float* __restrict__ probs,
    const short* __restrict__ Gd1p, const float* __restrict__ gd1b,
    const short* __restrict__ Gd2p, const float* __restrict__ gd2b,
    float* __restrict__ gs_out, short* __restrict__ gs16) {
  __shared__ short mid[64 * 256];   // 32 KB, 512B rows, XOR-swizzled
  const int tid = threadIdx.x;
  const int wave = tid >> 6, lane = tid & 63;
  const int cl = lane & 15, kg = lane >> 4;
  const int row0g = blockIdx.x * 64;
  const int row0l = wave * 16;

  // ===== se1 -> mid =====
  {
    short8_t ah1[2];
    {
      const short* ap = SI + (size_t)(row0g + row0l + cl) * 64;
#pragma unroll
      for (int kk = 0; kk < 2; ++kk)
        ah1[kk] = *(const short8_t*)(ap + kk * 32 + kg * 8);
    }
    for (int ct = 0; ct < 16; ++ct) {
      f32x4_t a0 = (f32x4_t){0.f, 0.f, 0.f, 0.f};
#pragma unroll
      for (int kk = 0; kk < 2; ++kk) {
        short8_t b_h = *(const short8_t*)(Se1p + (((size_t)ct * 2 + kk) * 64 + lane) * 8);
        MFMA(a0, ah1[kk], b_h);
      }
      int col = ct * 16 + cl;
      float bv = se1b[col];
      int c2hi = (col * 2) & ~15, c2lo = (col * 2) & 15;
#pragma unroll
      for (int j = 0; j < 4; ++j) {
        float v0 = fmaxf(a0[j] + bv, 0.f);
        int r0 = row0l + kg * 4 + j;
        int ad0 = ((r0 * 512 + c2hi) ^ ((r0 & 7) << 4)) + c2lo;
        *(short*)((char*)mid + ad0) = f2bf(v0);
      }
    }
  }
  __syncthreads();

  // ===== se2 -> sf (back into mid) =====
  {
    short8_t ah2[8];
    {
      int row = row0l + cl;
#pragma unroll
      for (int kk = 0; kk < 8; ++kk) {
        int ad = (row * 512 + kk * 64 + kg * 16) ^ ((row & 7) << 4);
        ah2[kk] = *(const short8_t*)((const char*)mid + ad);
      }
    }
    __syncthreads();  // all mid reads done; region reusable as sf
    for (int ct = 0; ct < 16; ++ct) {
      f32x4_t a0 = (f32x4_t){0.f, 0.f, 0.f, 0.f};
#pragma unroll
      for (int kk = 0; kk < 8; ++kk) {
        short8_t b_h = *(const short8_t*)(Se2p + (((size_t)ct * 8 + kk) * 64 + lane) * 8);
        MFMA(a0, ah2[kk], b_h);
      }
      int col = ct * 16 + cl;
      float bv = se2b[col];
      int c2hi = (col * 2) & ~15, c2lo = (col * 2) & 15;
#pragma unroll
      for (int j = 0; j < 4; ++j) {
        float v0 = fast_tanh(a0[j] + bv);
        int r0 = row0l + kg * 4 + j;
        int ad0 = ((r0 * 512 + c2hi) ^ ((r0 & 7) << 4)) + c2lo;
        *(short*)((char*)mid + ad0) = f2bf(v0);
      }
    }
  }
  __syncthreads();

  // ===== group assign -> probs + t frags =====
  short8_t tfr[8];
  {
    short8_t sfr[8];
    float lg[3] = {};
    {
      int row = row0l + cl;
#pragma unroll
      for (int kk = 0; kk < 8; ++kk) {
        int ad = (row * 512 + kk * 64 + kg * 16) ^ ((row & 7) << 4);
        short8_t s = *(const short8_t*)((const char*)mid + ad);
        sfr[kk] = s;
        int e0 = kk * 32 + kg * 8;
#pragma unroll
        for (int i = 0; i < 8; ++i) {
          float v = bf2f(s[i]);
          lg[0] = fmaf(v, ga_w[(e0 + i) * 3 + 0], lg[0]);
          lg[1] = fmaf(v, ga_w[(e0 + i) * 3 + 1], lg[1]);
          lg[2] = fmaf(v, ga_w[(e0 + i) * 3 + 2], lg[2]);
        }
      }
    }
#pragma unroll
    for (int g = 0; g < 3; ++g) {
      lg[g] += __shfl_xor(lg[g], 16, 64);
      lg[g] += __shfl_xor(lg[g], 32, 64);
    }
    float l0 = lg[0] + ga_b[0], l1 = lg[1] + ga_b[1], l2 = lg[2] + ga_b[2];
    float mx = fmaxf(l0, fmaxf(l1, l2));
    float e0 = __expf(l0 - mx), e1 = __expf(l1 - mx), e2 = __expf(l2 - mx);
    float inv = frcp_(e0 + e1 + e2);
    float p0 = e0 * inv, p1 = e1 * inv, p2 = e2 * inv;
    if (kg == 0) {
      size_t r = (size_t)(row0g + row0l + cl) * 3;
      probs[r + 0] = p0;
      probs[r + 1] = p1;
      probs[r + 2] = p2;
    }
#pragma unroll
    for (int kk = 0; kk < 8; ++kk) {
      int e0i = kk * 32 + kg * 8;
      short8_t tf;
#pragma unroll
      for (int i = 0; i < 8; ++i) {
        float tv = bf2f(sfr[kk][i]) + p0 * gemb[e0i + i] +
                   p1 * gemb[256 + e0i + i] + p2 * gemb[512 + e0i + i];
        tf[i] = f2bf(tv);
      }
      tfr[kk] = tf;
    }
  }
  __syncthreads();  // all sf reads done; mid region reusable

  // ===== gd1 -> mid, gd2 -> gs_out f32 + gs16 bf16 =====
  for (int ct = 0; ct < 16; ++ct) {
    f32x4_t a0 = (f32x4_t){0.f, 0.f, 0.f, 0.f};
#pragma unroll
    for (int kk = 0; kk < 8; ++kk) {
      short8_t b_h = *(const short8_t*)(Gd1p + (((size_t)ct * 8 + kk) * 64 + lane) * 8);
      MFMA(a0, tfr[kk], b_h);
    }
    int col = ct * 16 + cl;
    float bv = gd1b[col];
    int c2hi = (col * 2) & ~15, c2lo = (col * 2) & 15;
#pragma unroll
    for (int j = 0; j < 4; ++j) {
      float v0 = fmaxf(a0[j] + bv, 0.f);
      int r0 = row0l + kg * 4 + j;
      int ad0 = ((r0 * 512 + c2hi) ^ ((r0 & 7) << 4)) + c2lo;
      *(short*)((char*)mid + ad0) = f2bf(v0);
    }
  }
  __syncthreads();
  {
    short8_t ah2[8];
    {
      int row = row0l + cl;
#pragma unroll
      for (int kk = 0; kk < 8; ++kk) {
        int ad = (row * 512 + kk * 64 + kg * 16) ^ ((row & 7) << 4);
        ah2[kk] = *(const short8_t*)((const char*)mid + ad);
      }
    }
    for (int ct = 0; ct < 16; ++ct) {
      f32x4_t a0 = (f32x4_t){0.f, 0.f, 0.f, 0.f};
#pragma unroll
      for (int kk = 0; kk < 8; ++kk) {
        short8_t b_h = *(const short8_t*)(Gd2p + (((size_t)ct * 8 + kk) * 64 + lane) * 8);
        MFMA(a0, ah2[kk], b_h);
      }
      int col = ct * 16 + cl;
      float bv = gd2b[col];
#pragma unroll
      for (int j = 0; j < 4; ++j) {
        float v0 = fast_tanh(a0[j] + bv);
        size_t r0 = (size_t)(row0g + row0l + kg * 4 + j) * 256 + col;
        gs_out[r0] = v0;
        gs16[r0] = f2bf(v0);
      }
    }
  }
}

// ---------------- MFMA hypernet q v12: h16 input, DMA dbuf, bias-in-C ----------------
__global__ __launch_bounds__(256, 2) void hyper_q_v12_kernel(
    const short* __restrict__ GS16, const short* __restrict__ H16,
    const short* __restrict__ Wp, const float* __restrict__ hwb,
    float* __restrict__ Qpart) {
  __shared__ short Bh[2][8192];        // 32 KB: two ct-pair buffers
  __shared__ short h_lds[4][64][68];   // 34 KB, col-major: [wave][col][row], stride 68
  const int tid = threadIdx.x;
  const int wave = tid >> 6, lane = tid & 63;
  const int cl = lane & 15, kg = lane >> 4;
  const int half = blockIdx.x >> 8;
  const int wrow = (blockIdx.x & 255) * 256 + wave * 64;
  const int ct_base = half * 128;

  // ---- stage h block col-major from h16: lane owns row `lane` ----
  {
    const short* hp = H16 + (size_t)(wrow + lane) * 128 + half * 64;
#pragma unroll
    for (int c = 0; c < 64; c += 8) {
      short8_t v = *(const short8_t*)(hp + c);
#pragma unroll
      for (int i = 0; i < 8; ++i) h_lds[wave][c + i][lane] = v[i];
    }
  }

  // ---- A (gs bf16) -> registers: 4 m-frags x 8 kk ----
  short8_t ah[4][8];
#pragma unroll
  for (int m = 0; m < 4; ++m) {
    const short* ap = GS16 + (size_t)(wrow + m * 16 + cl) * 256;
#pragma unroll
    for (int kk = 0; kk < 8; ++kk) ah[m][kk] = *(const short8_t*)(ap + kk * 32 + kg * 8);
  }

  // ---- prologue: DMA ct pair {base, base+1} into buf 0 ----
  {
    const short* wp0 = Wp + (size_t)ct_base * 4096;
#pragma unroll
    for (int k = 0; k < 4; ++k)
      async_cp16(wp0 + k * 2048 + tid * 8, &Bh[0][k * 2048 + tid * 8]);
  }
  __syncthreads();

  float qf[4][2][4] = {};
  int cur = 0;

#define COMPUTE_CT(BUFP, OH, WB)                                               \
  {                                                                            \
    f32x4_t acc[4];                                                            \
    _Pragma("unroll")                                                          \
    for (int m = 0; m < 4; ++m) acc[m] = (f32x4_t){(WB), (WB), (WB), (WB)};    \
    _Pragma("unroll")                                                          \
    for (int kk = 0; kk < 8; ++kk) {                                           \
      short8_t b_h = *(const short8_t*)((BUFP) + ((OH) * 4096 + (kk * 64 + lane) * 8)); \
      _Pragma("unroll")                                                        \
      for (int m = 0; m < 4; ++m) MFMA(acc[m], ah[m][kk], b_h);                \
    }                                                                          \
    _Pragma("unroll")                                                          \
    for (int m = 0; m < 4; ++m)                                                \
      _Pragma("unroll")                                                        \
      for (int j = 0; j < 4; ++j)                                              \
        qf[m][OH][j] = fmaf(hc[m * 4 + j], acc[m][j], qf[m][OH][j]);           \
  }

  for (int t2 = 0; t2 < 64; ++t2) {
    const int ct0 = ct_base + t2 * 2;
    // issue DMA for next ct pair into the other buffer (drained by the barrier below)
    if (t2 < 63) {
      const short* wpn = Wp + (size_t)(ct0 + 2) * 4096;
      short* bufn = &Bh[cur ^ 1][0];
#pragma unroll
      for (int k = 0; k < 4; ++k)
        async_cp16(wpn + k * 2048 + tid * 8, bufn + k * 2048 + tid * 8);
    }
    // h column t2: 4 broadcast b64 reads (per m, 4 consecutive rows)
    float hc[16];
#pragma unroll
    for (int m = 0; m < 4; ++m) {
      short4_t v4 = *(const short4_t*)&h_lds[wave][t2][m * 16 + kg * 4];
#pragma unroll
      for (int j = 0; j < 4; ++j) hc[m * 4 + j] = bf2f(v4[j]);
    }
    float wb0 = hwb[ct0 * 16 + cl];
    float wb1 = hwb[(ct0 + 1) * 16 + cl];
    const short* bufp = &Bh[cur][0];
    COMPUTE_CT(bufp, 0, wb0)
    COMPUTE_CT(bufp, 1, wb1)
    __syncthreads();
    cur ^= 1;
  }
#undef COMPUTE_CT

  // ---- half 0 adds fc2_b = gs @ hb_w via packed chunks 256/257 (direct L2) ----
  if (half == 0) {
#pragma unroll
    for (int oh = 0; oh < 2; ++oh) {
      f32x4_t bacc[4];
#pragma unroll
      for (int m = 0; m < 4; ++m) bacc[m] = (f32x4_t){0.f, 0.f, 0.f, 0.f};
#pragma unroll
      for (int kk = 0; kk < 8; ++kk) {
        short8_t b_h = *(const short8_t*)(Wp + (((size_t)(256 + oh) * 8 + kk) * 64 + lane) * 8);
#pragma unroll
        for (int m = 0; m < 4; ++m) MFMA(bacc[m], ah[m][kk], b_h);
      }
#pragma unroll
      for (int m = 0; m < 4; ++m)
#pragma unroll
        for (int j = 0; j < 4; ++j) qf[m][oh][j] += bacc[m][j];
    }
  }

  // ---- write partial q ----
  float* qp = Qpart + (size_t)half * 2097152;
#pragma unroll
  for (int m = 0; m < 4; ++m)
#pragma unroll
    for (int j = 0; j < 4; ++j) {
      const size_t r = (size_t)(wrow + m * 16 + kg * 4 + j) * 32;
      qp[r + cl] = qf[m][0][j];
      qp[r + 16 + cl] = qf[m][1][j];
    }
}

// ---------------- combine: q = qpart0 + qpart1 + hb_b ----------------
__global__ __launch_bounds__(256) void qcombine_kernel(
    const float* __restrict__ Qpart, const float* __restrict__ hbb,
    float* __restrict__ Qout) {
  int i = blockIdx.x * 256 + threadIdx.x;  // 524288 float4s
  float4 a = ((const float4*)Qpart)[i];
  float4 b = ((const float4*)(Qpart + 2097152))[i];
  float4 e = ((const float4*)hbb)[i & 7];
  ((float4*)Qout)[i] = make_float4(a.x + b.x + e.x, a.y + b.y + e.y,
                                   a.z + b.z + e.z, a.w + b.w + e.w);
}

extern "C" void kernel_launch(void* const* d_in, const int* in_sizes, int n_in,
                              void* d_out, int out_size, void* d_ws, size_t ws_size,
                              hipStream_t stream) {
  const float* inputs   = (const float*)d_in[0];
  const float* hidden   = (const float*)d_in[1];
  const float* fc1_w    = (const float*)d_in[2];
  const float* fc1_b    = (const float*)d_in[3];
  const float* gru_wi   = (const float*)d_in[4];
  const float* gru_wh   = (const float*)d_in[5];
  const float* gru_bi   = (const float*)d_in[6];
  const float* gru_bh   = (const float*)d_in[7];
  const float* attn_q_w = (const float*)d_in[8];
  const float* attn_k_w = (const float*)d_in[9];
  const float* se1_w    = (const float*)d_in[10];
  const float* se1_b    = (const float*)d_in[11];
  const float* se2_w    = (const float*)d_in[12];
  const float* se2_b    = (const float*)d_in[13];
  const float* ga_w     = (const float*)d_in[14];
  const float* ga_b     = (const float*)d_in[15];
  const float* gemb     = (const float*)d_in[16];
  const float* gd1_w    = (const float*)d_in[17];
  const float* gd1_b    = (const float*)d_in[18];
  const float* gd2_w    = (const float*)d_in[19];
  const float* gd2_b    = (const float*)d_in[20];
  const float* hb_w     = (const float*)d_in[21];
  const float* hb_b     = (const float*)d_in[22];
  const float* hw_w     = (const float*)d_in[23];
  const float* hw_b     = (const float*)d_in[24];

  float* out = (float*)d_out;
  float* q_out     = out;              // [R,32]
  float* h_out     = out + 2097152;    // [R,128]
  float* gs_out    = out + 10485760;   // [R,256]
  float* probs_out = out + 27262976;   // [R,3]
  float* attn_out  = out + 27459584;   // [B,32,32]

  // workspace layout (bytes), all regions disjoint:
  //   [0,16M):   qpart f32 [2][R,32]
  //   [16M,24M): si bf16 [R,64]
  //   [24M,56M): gs16 bf16 [R,256]
  //   [56M,72M): h16 bf16 [R,128]
  //   [72M,+2.9M): packs
  char* wsb = (char*)d_ws;
  float* qpart = (float*)wsb;
  short* si   = (short*)(wsb + (size_t)16 * 1024 * 1024);
  short* gs16 = (short*)(wsb + (size_t)24 * 1024 * 1024);
  short* h16  = (short*)(wsb + (size_t)56 * 1024 * 1024);
  short* P    = (short*)(wsb + (size_t)72 * 1024 * 1024);

  // pack offsets (shorts); chunk = KK*512 shorts
  const size_t o_hw  = 0;        // K=256 KK=8, N=4096 (+hb chunks 256..257)
  const size_t o_hb  = 1048576;
  const size_t o_fc1 = 1056768;
  const size_t o_wi  = 1077248;
  const size_t o_wh  = 1126400;
  const size_t o_qkq = 1175552;
  const size_t o_qkk = 1191936;  // must be o_qkq + 16384 (attn assumes contiguity)
  const size_t o_se1 = 1208320;
  const size_t o_se2 = 1224704;
  const size_t o_gd1 = 1290240;
  const size_t o_gd2 = 1355776;

  PackArgs pa;
  pa.s[0]  = {hw_w,     256, 4096, 8, 0,    4096, o_hw};
  pa.s[1]  = {hb_w,     256, 32,   8, 4096, 32,   o_hb};
  pa.s[2]  = {fc1_w,    160, 128,  5, 4128, 80,   o_fc1};
  pa.s[3]  = {gru_wi,   128, 384,  4, 4208, 192,  o_wi};
  pa.s[4]  = {gru_wh,   128, 384,  4, 4400, 192,  o_wh};
  pa.s[5]  = {attn_q_w, 128, 128,  4, 4592, 64,   o_qkq};
  pa.s[6]  = {attn_k_w, 128, 128,  4, 4656, 64,   o_qkk};
  pa.s[7]  = {se1_w,    34,  256,  2, 4720, 64,   o_se1};
  pa.s[8]  = {se2_w,    256, 256,  8, 4784, 256,  o_se2};
  pa.s[9]  = {gd1_w,    256, 256,  8, 5040, 256,  o_gd1};
  pa.s[10] = {gd2_w,    256, 256,  8, 5296, 256,  o_gd2};

  dim3 blk(256);
  // 0) pack ALL weights in one launch
  pack_all_kernel<<<5552, blk, 0, stream>>>(pa, P);
  // 1) h = GRUCell(relu(inputs@fc1+b), hidden) -> h_out f32 + h16 bf16
  gru_fused_kernel<<<1024, blk, 0, stream>>>(inputs, hidden, P + o_fc1, fc1_b,
                                             P + o_wi, P + o_wh, gru_bi, gru_bh,
                                             h_out, h16);
  // 2) attention v3 (h16 input, fused tail) -> attn_out f32 + si bf16
  attn_fused_kernel<<<2048, blk, 0, stream>>>(h16, P + o_qkq, attn_out, si);
  // 3) se1+se2+group+gd1+gd2 fused -> probs + gs_out f32 + gs16 bf16
  se_gd_kernel<<<1024, blk, 0, stream>>>(si, P + o_se1, se1_b, P + o_se2, se2_b,
                                         ga_w, ga_b, gemb, probs_out,
                                         P + o_gd1, gd1_b, P + o_gd2, gd2_b,
                                         gs_out, gs16);
  // 4) q partials: half-split, h16 LDS, async-DMA ct-pair dbuf
  hyper_q_v12_kernel<<<dim3(512), blk, 0, stream>>>(gs16, h16, P + o_hw, hw_b, qpart);
  // 5) q = qpart0 + qpart1 + hb_b
  qcombine_kernel<<<2048, blk, 0, stream>>>(qpart, hb_b, q_out);
}